// Round 4
// baseline (923.621 us; speedup 1.0000x reference)
//
#include <hip/hip_runtime.h>

// GraphSAGE 3-layer, fp32.
// Linearity: segsum(Wm@concat(nf[src],ef)) == Wm_n@segsum(nf[src]) + Wm_e@segsum(ef) + deg*bm
// CSR build on device -> atomic-free gather aggregations + tiled SGEMMs.
// Round 3->4: GEMM 64x64/4x4 was LDS-issue bound (FMA:LDS cyc ~256:370/wave-iter).
// Now 128x64 tile, 8x4 microtile (32 FMA : 3 ds_read_b128 per k). Agg<152> lane
// occupancy 38/64 -> 57/64 via 8-float chunks.

#define NN 50000
#define NE 800000
#define NIN 64
#define EDIM_ 64
#define HID_ 152
#define NOUT 64
#define PADN 50176   // 49 * 1024

// ---------------- histogram: integer in-degree ----------------
__global__ __launch_bounds__(256) void hist_kernel(const int* __restrict__ dst,
                                                   int* __restrict__ ideg) {
    int e = blockIdx.x * 256 + threadIdx.x;
    if (e < NE) atomicAdd(&ideg[dst[e]], 1);
}

// ---------------- exclusive scan, 3 kernels ----------------
__global__ __launch_bounds__(256) void scan1_kernel(const int* __restrict__ in,
                                                    int* __restrict__ out,
                                                    int* __restrict__ bsum) {
    __shared__ int ws[4];
    int t = threadIdx.x;
    int base = blockIdx.x * 1024 + t * 4;
    int a0 = in[base], a1 = in[base + 1], a2 = in[base + 2], a3 = in[base + 3];
    int s = a0 + a1 + a2 + a3;
    int lane = t & 63, wid = t >> 6;
    int v = s;
#pragma unroll
    for (int d = 1; d < 64; d <<= 1) {
        int u = __shfl_up(v, d);
        if (lane >= d) v += u;
    }
    if (lane == 63) ws[wid] = v;
    __syncthreads();
    int wofs = 0;
    if (wid > 0) wofs += ws[0];
    if (wid > 1) wofs += ws[1];
    if (wid > 2) wofs += ws[2];
    int excl = wofs + v - s;
    out[base] = excl;
    out[base + 1] = excl + a0;
    out[base + 2] = excl + a0 + a1;
    out[base + 3] = excl + a0 + a1 + a2;
    if (t == 255) bsum[blockIdx.x] = wofs + v;
}

__global__ __launch_bounds__(64) void scan2_kernel(int* __restrict__ bsum, int nb) {
    int t = threadIdx.x;
    int orig = (t < nb) ? bsum[t] : 0;
    int v = orig;
#pragma unroll
    for (int d = 1; d < 64; d <<= 1) {
        int u = __shfl_up(v, d);
        if (t >= d) v += u;
    }
    if (t < nb) bsum[t] = v - orig;
}

__global__ __launch_bounds__(256) void scan3_kernel(int* __restrict__ out,
                                                    const int* __restrict__ bsum) {
    int base = blockIdx.x * 1024 + threadIdx.x * 4;
    int b = bsum[blockIdx.x];
    out[base] += b; out[base + 1] += b; out[base + 2] += b; out[base + 3] += b;
}

// ---------------- scatter edges into CSR order ----------------
__global__ __launch_bounds__(256) void scatter_edges_kernel(const int* __restrict__ src,
                                                            const int* __restrict__ dst,
                                                            int* __restrict__ cursor,
                                                            int* __restrict__ csr_nf,
                                                            int* __restrict__ csr_ef) {
    int e = blockIdx.x * 256 + threadIdx.x;
    if (e >= NE) return;
    int d = dst[e];
    int pos = atomicAdd(&cursor[d], 1);
    csr_nf[pos] = src[e];
    csr_ef[pos] = e;
}

// ---------------- gather-sum aggregation ----------------
// out[n][0:F] = sum over CSR segment of table[rows[i]][0:F]
// 8-float chunk per lane: C = F/8 chunks, NPW = 64/C nodes per wave.
template <int F>
__global__ __launch_bounds__(256) void agg_kernel(const float* __restrict__ table,
                                                  const int* __restrict__ rows,
                                                  const int* __restrict__ off,
                                                  float* __restrict__ out) {
    constexpr int C = F / 8;          // 19 for F=152, 8 for F=64
    constexpr int NPW = 64 / C;       // 3 for F=152, 8 for F=64
    int t = threadIdx.x;
    int lane = t & 63, wid = t >> 6;
    int sub = lane / C;
    int ch = lane - sub * C;
    int n = (blockIdx.x * 4 + wid) * NPW + sub;
    if (sub >= NPW || n >= NN) return;
    int s = off[n], e = off[n + 1];
    float4 a0 = {0,0,0,0}, a1 = {0,0,0,0}, b0 = {0,0,0,0}, b1 = {0,0,0,0};
    int i = s;
    for (; i + 1 < e; i += 2) {
        const float* p0 = table + (size_t)rows[i] * F + ch * 8;
        const float* p1 = table + (size_t)rows[i + 1] * F + ch * 8;
        float4 u0 = *(const float4*)p0;
        float4 u1 = *(const float4*)(p0 + 4);
        float4 v0 = *(const float4*)p1;
        float4 v1 = *(const float4*)(p1 + 4);
        a0.x += u0.x; a0.y += u0.y; a0.z += u0.z; a0.w += u0.w;
        a1.x += u1.x; a1.y += u1.y; a1.z += u1.z; a1.w += u1.w;
        b0.x += v0.x; b0.y += v0.y; b0.z += v0.z; b0.w += v0.w;
        b1.x += v1.x; b1.y += v1.y; b1.z += v1.z; b1.w += v1.w;
    }
    if (i < e) {
        const float* p0 = table + (size_t)rows[i] * F + ch * 8;
        float4 u0 = *(const float4*)p0;
        float4 u1 = *(const float4*)(p0 + 4);
        a0.x += u0.x; a0.y += u0.y; a0.z += u0.z; a0.w += u0.w;
        a1.x += u1.x; a1.y += u1.y; a1.z += u1.z; a1.w += u1.w;
    }
    float4 r0, r1;
    r0.x = a0.x + b0.x; r0.y = a0.y + b0.y; r0.z = a0.z + b0.z; r0.w = a0.w + b0.w;
    r1.x = a1.x + b1.x; r1.y = a1.y + b1.y; r1.z = a1.z + b1.z; r1.w = a1.w + b1.w;
    float* o = out + (size_t)n * F + ch * 8;
    *(float4*)o = r0;
    *(float4*)(o + 4) = r1;
}

// ---------------- tiled SGEMM, 128x64 tile, 8x4 microtile, fused epilogue ----
// out[M x NT] = concat(X1[MxK1], X2[MxK2]) @ W^T + epilogue
// MSG: (acc + deg*bias)/max(deg,1), deg = off[n+1]-off[n];  !MSG: relu(acc + bias)
template <int K1, int K2, int NT, bool MSG>
__global__ __launch_bounds__(256) void gemm_kernel(const float* __restrict__ X1,
                                                   const float* __restrict__ X2,
                                                   const float* __restrict__ W,
                                                   const float* __restrict__ bias,
                                                   const int* __restrict__ off,
                                                   float* __restrict__ out) {
    constexpr int KT = K1 + K2;
    __shared__ float Xs[8][132];   // [k][m], 132*4 % 16 == 0 -> b128-aligned rows
    __shared__ float Ws[8][68];    // [k][o]
    const int t = threadIdx.x;
    const int m0 = blockIdx.x * 128;
    const int n0 = blockIdx.y * 64;
    // X staging: row = t>>1 (0..127), half = t&1 -> float4 along k
    const int xrow = t >> 1;
    const int xk = (t & 1) * 4;
    // W staging: row = t>>2 (0..63), float2 along k
    const int wrow = t >> 2;
    const int wk = (t & 3) * 2;
    const int tx = t & 15;         // col group (4 cols)
    const int ty = t >> 4;         // row group (8 rows)
    float acc[8][4] = {};

    const bool xrow_ok = (m0 + xrow) < NN;
    const bool wrow_ok = (n0 + wrow) < NT;

#pragma unroll
    for (int seg = 0; seg < 2; ++seg) {
        const float* __restrict__ X = seg ? X2 : X1;
        const int K = seg ? K2 : K1;
        const int koff = seg ? K1 : 0;
        for (int k0 = 0; k0 < K; k0 += 8) {
            float4 xv = make_float4(0.f, 0.f, 0.f, 0.f);
            if (xrow_ok) xv = *(const float4*)(X + (size_t)(m0 + xrow) * K + k0 + xk);
            float2 wv = make_float2(0.f, 0.f);
            if (wrow_ok) wv = *(const float2*)(W + (size_t)(n0 + wrow) * KT + koff + k0 + wk);
            __syncthreads();
            Xs[xk][xrow] = xv.x; Xs[xk + 1][xrow] = xv.y;
            Xs[xk + 2][xrow] = xv.z; Xs[xk + 3][xrow] = xv.w;
            Ws[wk][wrow] = wv.x; Ws[wk + 1][wrow] = wv.y;
            __syncthreads();
#pragma unroll
            for (int k = 0; k < 8; ++k) {
                float4 a0 = *(const float4*)&Xs[k][ty * 8];
                float4 a1 = *(const float4*)&Xs[k][ty * 8 + 4];
                float4 b = *(const float4*)&Ws[k][tx * 4];
                acc[0][0] += a0.x * b.x; acc[0][1] += a0.x * b.y; acc[0][2] += a0.x * b.z; acc[0][3] += a0.x * b.w;
                acc[1][0] += a0.y * b.x; acc[1][1] += a0.y * b.y; acc[1][2] += a0.y * b.z; acc[1][3] += a0.y * b.w;
                acc[2][0] += a0.z * b.x; acc[2][1] += a0.z * b.y; acc[2][2] += a0.z * b.z; acc[2][3] += a0.z * b.w;
                acc[3][0] += a0.w * b.x; acc[3][1] += a0.w * b.y; acc[3][2] += a0.w * b.z; acc[3][3] += a0.w * b.w;
                acc[4][0] += a1.x * b.x; acc[4][1] += a1.x * b.y; acc[4][2] += a1.x * b.z; acc[4][3] += a1.x * b.w;
                acc[5][0] += a1.y * b.x; acc[5][1] += a1.y * b.y; acc[5][2] += a1.y * b.z; acc[5][3] += a1.y * b.w;
                acc[6][0] += a1.z * b.x; acc[6][1] += a1.z * b.y; acc[6][2] += a1.z * b.z; acc[6][3] += a1.z * b.w;
                acc[7][0] += a1.w * b.x; acc[7][1] += a1.w * b.y; acc[7][2] += a1.w * b.z; acc[7][3] += a1.w * b.w;
            }
        }
    }

    const int o0 = n0 + tx * 4;
    if (o0 >= NT) return;
    float b0 = bias[o0], b1 = bias[o0 + 1], b2 = bias[o0 + 2], b3 = bias[o0 + 3];
#pragma unroll
    for (int i = 0; i < 8; ++i) {
        int n = m0 + ty * 8 + i;
        if (n >= NN) break;
        float4 r;
        if (MSG) {
            float d = (float)(off[n + 1] - off[n]);
            float inv = 1.0f / fmaxf(d, 1.0f);
            r.x = (acc[i][0] + d * b0) * inv;
            r.y = (acc[i][1] + d * b1) * inv;
            r.z = (acc[i][2] + d * b2) * inv;
            r.w = (acc[i][3] + d * b3) * inv;
        } else {
            r.x = fmaxf(acc[i][0] + b0, 0.0f);
            r.y = fmaxf(acc[i][1] + b1, 0.0f);
            r.z = fmaxf(acc[i][2] + b2, 0.0f);
            r.w = fmaxf(acc[i][3] + b3, 0.0f);
        }
        *(float4*)(out + (size_t)n * NT + o0) = r;
    }
}

extern "C" void kernel_launch(void* const* d_in, const int* in_sizes, int n_in,
                              void* d_out, int out_size, void* d_ws, size_t ws_size,
                              hipStream_t stream) {
    const float* nfeats = (const float*)d_in[0];
    const float* efeats = (const float*)d_in[1];
    const float* Wm1 = (const float*)d_in[2];
    const float* bm1 = (const float*)d_in[3];
    const float* Wa1 = (const float*)d_in[4];
    const float* ba1 = (const float*)d_in[5];
    const float* Wm2 = (const float*)d_in[6];
    const float* bm2 = (const float*)d_in[7];
    const float* Wa2 = (const float*)d_in[8];
    const float* ba2 = (const float*)d_in[9];
    const float* Wm3 = (const float*)d_in[10];
    const float* bm3 = (const float*)d_in[11];
    const float* Wa3 = (const float*)d_in[12];
    const float* ba3 = (const float*)d_in[13];
    const int* src = (const int*)d_in[14];
    const int* dst = (const int*)d_in[15];
    float* out = (float*)d_out;

    int* iws = (int*)d_ws;
    int* ideg   = iws;                  // PADN
    int* off    = iws + PADN;           // PADN
    int* cursor = iws + 2 * PADN;       // PADN
    int* csr_nf = iws + 3 * PADN;       // NE
    int* csr_ef = csr_nf + NE;          // NE
    float* B = (float*)(csr_ef + NE);   // NN*64
    float* P = B + 3200000;             // NN*152
    float* Q = P + 7600000;             // NN*152
    float* R = Q + 7600000;             // NN*152

    const int BLK = 256;
    auto cdiv = [](long long a, long long b) { return (int)((a + b - 1) / b); };
    dim3 g152(cdiv(NN, 128), cdiv(152, 64));   // 391 x 3
    dim3 g64(cdiv(NN, 128), 1);                // 391 x 1
    const int NB = PADN / 1024;  // 49

    // ---- CSR build ----
    hipMemsetAsync(ideg, 0, (size_t)PADN * 4, stream);
    hist_kernel<<<cdiv(NE, BLK), BLK, 0, stream>>>(dst, ideg);
    scan1_kernel<<<NB, 256, 0, stream>>>(ideg, off, cursor);
    scan2_kernel<<<1, 64, 0, stream>>>(cursor, NB);
    scan3_kernel<<<NB, 256, 0, stream>>>(off, cursor);
    hipMemcpyAsync(cursor, off, (size_t)NN * 4, hipMemcpyDeviceToDevice, stream);
    scatter_edges_kernel<<<cdiv(NE, BLK), BLK, 0, stream>>>(src, dst, cursor, csr_nf, csr_ef);

    // ---- layer-invariant: B = segsum(ef) ----
    agg_kernel<EDIM_><<<cdiv(NN, 32), BLK, 0, stream>>>(efeats, csr_ef, off, B);

    // ---- layer 1 ----
    agg_kernel<NIN><<<cdiv(NN, 32), BLK, 0, stream>>>(nfeats, csr_nf, off, P);
    gemm_kernel<NIN, EDIM_, HID_, true><<<g152, BLK, 0, stream>>>(P, B, Wm1, bm1, off, Q);
    gemm_kernel<NIN, HID_, HID_, false><<<g152, BLK, 0, stream>>>(nfeats, Q, Wa1, ba1, off, R);  // h1 = R

    // ---- layer 2 ----
    agg_kernel<HID_><<<cdiv(NN, 12), BLK, 0, stream>>>(R, csr_nf, off, P);
    gemm_kernel<HID_, EDIM_, HID_, true><<<g152, BLK, 0, stream>>>(P, B, Wm2, bm2, off, Q);
    gemm_kernel<HID_, HID_, HID_, false><<<g152, BLK, 0, stream>>>(R, Q, Wa2, ba2, off, P);      // h2 = P

    // ---- layer 3 ----
    agg_kernel<HID_><<<cdiv(NN, 12), BLK, 0, stream>>>(P, csr_nf, off, Q);
    gemm_kernel<HID_, EDIM_, NOUT, true><<<g64, BLK, 0, stream>>>(Q, B, Wm3, bm3, off, R);       // hn3 = R
    gemm_kernel<HID_, NOUT, NOUT, false><<<g64, BLK, 0, stream>>>(P, R, Wa3, ba3, off, out);
}